// Round 2
// baseline (85.921 us; speedup 1.0000x reference)
//
#include <hip/hip_runtime.h>
#include <math.h>

#define NMAX   64
#define NSITES 12
#define SPLIT  2      // threads per batch element (6 sites each)
#define BLOCK  256

#define B_SOFT 0.01f
#define PAD_C  4.0e4f   // sentinel coord -> r2 ~ 3e9 -> clamped -> last bin
#define R2_MAX 248.0f   // bits 0x43780000 -> entry 6136 (last used)
#define R2_MIN_BITS 0x2B800000u   // 2^-40; clamp floor

// Piecewise-CONSTANT table, 128 bins/octave: entry i covers r2-bits in
// [R2_MIN_BITS + (i<<16), +(1<<16)).  c_i = (f(lo)+f(hi))/2 is L-inf
// optimal for monotone f; per-term error |f'(r)|*r/512 (max ~0.05 at
// r~0.01, typical ~3e-4) -> batch absmax ~0.1 << 0.5 tolerance.
// Gather becomes ds_read_b32 (256B/wave, ~2x less LDS pipe than b64 lerp).
#define TBL_N     6144            // entries 0..6136 used
#define TBL_BYTES (TBL_N * 4)     // 24576

// Neighbor AoS rows: (x,y) pairs compacted per site.  Row stride 528B so
// the two site rows read per wave-op (site and site+6, lane parity) sit
// 792 words = 24 banks apart -> disjoint b128 spans, conflict-free.
#define NPAIR  66                 // pairs per row (>= padded count 64)
#define ROWF   (NPAIR * 2)        // 132 floats = 528 B
#define NB_F   (NSITES * ROWF)    // 1584 floats
#define WS_F   (TBL_N + NB_F)     // device-global scratch floats
#define SMEM_F WS_F               // 30912 B LDS -> 4 blocks/CU (grid-exact)

__device__ __align__(16) float g_ws[WS_F];   // [0,TBL_N) table | neighbors
__device__ int g_m;

typedef float v4f __attribute__((ext_vector_type(4)));

// f(r2) = exp(-sqrt(r2)) / (sqrt(r2) + b), exact (init kernel only)
__device__ __forceinline__ float f_exact(float r2) {
    const float r = sqrtf(r2);
    return expf(-r) / (r + B_SOFT);
}

#define INIT_BLOCKS 25   // 25*256 = 6400 >= TBL_N table slots

// Build table (all blocks, disjoint slices) + compact neighbors (block 0).
__global__ void init_kernel(const float* __restrict__ neighbors,
                            const float* __restrict__ mask) {
    const int tid = threadIdx.x;
    const int gid = blockIdx.x * BLOCK + tid;

    if (gid < TBL_N) {
        const unsigned b0 = R2_MIN_BITS + ((unsigned)gid << 16);
        const unsigned b1 = b0 + (1u << 16);
        const float f0 = f_exact(__builtin_bit_cast(float, b0));
        const float f1 = f_exact(__builtin_bit_cast(float, b1));
        g_ws[gid] = 0.5f * (f0 + f1);
    }

    if (blockIdx.x == 0) {
        __shared__ int cnt[NSITES];
        // Sentinel fill: slots past a site's count give r2~3e9 -> clamped
        // -> last bin -> ~9e-9 each (negligible).
        for (int i = tid; i < NB_F; i += BLOCK) g_ws[TBL_N + i] = PAD_C;
        __syncthreads();

        const int wv = tid >> 6, lane = tid & 63;
        for (int s = wv; s < NSITES; s += 4) {
            const bool keep = mask[s * NMAX + lane] > 0.5f;
            const unsigned long long bal = __ballot(keep);
            if (keep) {
                const int pos = __popcll(bal & ((1ull << lane) - 1ull));
                const float2 p = ((const float2*)neighbors)[s * NMAX + lane];
                g_ws[TBL_N + s * ROWF + 2 * pos]     = p.x;
                g_ws[TBL_N + s * ROWF + 2 * pos + 1] = p.y;
            }
            if (lane == 0) cnt[s] = __popcll(bal);
        }
        __syncthreads();
        if (tid == 0) {
            int m = 0;
            #pragma unroll
            for (int s = 0; s < NSITES; ++s) m = max(m, cnt[s]);
            g_m = (m + 3) & ~3;   // <= 64, row-safe
        }
    }
}

__global__ __launch_bounds__(BLOCK, 4)
void pot_energy_kernel(const float* __restrict__ x,
                       float* __restrict__ out, int B) {
    __shared__ __align__(16) float smem[SMEM_F];
    const int tid = threadIdx.x;

    // Prologue: copy table + neighbor rows from L2-hot device global.
    {
        const float4* s4 = (const float4*)g_ws;
        float4* d4 = (float4*)smem;
        for (int i = tid; i < WS_F / 4; i += BLOCK) d4[i] = s4[i];
    }
    const int m = g_m;          // uniform -> scalar load
    __syncthreads();

    const int gtid = blockIdx.x * BLOCK + tid;
    const int e = gtid >> 1;    // element
    const int q = gtid & 1;     // half: sites q*6 .. q*6+5
    if (e >= B) return;

    // This lane's 6 site positions: 12 contiguous floats, 16B-aligned.
    const float4* xp = (const float4*)(x + (size_t)e * 24 + q * 12);
    const float4 x0 = xp[0], x1 = xp[1], x2 = xp[2];
    const float xs_[6] = { x0.x, x0.z, x1.x, x1.z, x2.x, x2.z };
    const float ys_[6] = { x0.y, x0.w, x1.y, x1.w, x2.y, x2.w };

    const float R2MINF = __builtin_bit_cast(float, R2_MIN_BITS);

    float acc0 = 0.f, acc1 = 0.f;
    #pragma unroll
    for (int s = 0; s < 6; ++s) {
        const int site = q * 6 + s;
        const float xs = xs_[s];
        const float ys = ys_[s];
        const float* __restrict__ row = smem + TBL_N + site * ROWF;
        #pragma unroll 2
        for (int j0 = 0; j0 < m; j0 += 4) {
            // 2 reads x 2 AoS pairs; only 2 distinct wave addresses
            // (lane parity), disjoint banks -> broadcast, ~free.
            const v4f a = *(const v4f*)(row + 2 * j0);
            const v4f b = *(const v4f*)(row + 2 * j0 + 4);
            const float nx[4] = { a.x, a.z, b.x, b.z };
            const float ny[4] = { a.y, a.w, b.y, b.w };
            #pragma unroll
            for (int k = 0; k < 4; ++k) {
                const float dx = xs - nx[k];
                const float dy = ys - ny[k];
                float r2 = fmaf(dy, dy, dx * dx);
                // single med3 clamps both ends (sentinels AND tiny r2)
                r2 = __builtin_amdgcn_fmed3f(r2, R2MINF, R2_MAX);
                const unsigned t =
                    __builtin_bit_cast(unsigned, r2) - R2_MIN_BITS;
                const unsigned off = (t >> 14) & 0xFFFFFFFCu; // byte addr
                const float c = *(const float*)((const char*)smem + off);
                if (k & 1) acc1 += c; else acc0 += c;   // 2 chains for ILP
            }
        }
    }

    float acc = acc0 + acc1;
    acc += __shfl_xor(acc, 1);   // combine the 2 half-partials of element e
    if (q == 0) out[e] = acc;
}

extern "C" void kernel_launch(void* const* d_in, const int* in_sizes, int n_in,
                              void* d_out, int out_size, void* d_ws, size_t ws_size,
                              hipStream_t stream) {
    const float* x   = (const float*)d_in[0];
    const float* nbr = (const float*)d_in[1];
    const float* msk = (const float*)d_in[2];
    float* out = (float*)d_out;

    const int B = in_sizes[0] / 24;

    init_kernel<<<INIT_BLOCKS, BLOCK, 0, stream>>>(nbr, msk);

    const int total_threads = B * SPLIT;
    const int blocks = (total_threads + BLOCK - 1) / BLOCK;
    pot_energy_kernel<<<blocks, BLOCK, 0, stream>>>(x, out, B);
}